// Round 9
// baseline (142.309 us; speedup 1.0000x reference)
//
#include <hip/hip_runtime.h>
#include <hip/hip_bf16.h>
#include <stdint.h>

#define BN 8192
#define DK 256
#define KLOG2E_T 20.609929155556617f    // log2(e)/0.07
#define INV_T 14.285714285714286f       // 1/0.07
#define NEGINF (-3.0e38f)

typedef short vshort8 __attribute__((ext_vector_type(8)));
typedef float vfloat4 __attribute__((ext_vector_type(4)));

__device__ __forceinline__ void gload16(const void* g, void* lds) {
  __builtin_amdgcn_global_load_lds(
      (const __attribute__((address_space(1))) unsigned int*)g,
      (__attribute__((address_space(3))) unsigned int*)lds, 16, 0, 0);
}

// ---------- prep: fp32->bf16, keys, cntA, G partials (one kernel) ----------
__global__ __launch_bounds__(256) void prep_g(
    const float* __restrict__ P, const int* __restrict__ aff,
    const int* __restrict__ inst, ushort* __restrict__ Pb,
    int* __restrict__ keys, int* __restrict__ cntA, float* __restrict__ G) {
  __shared__ float4 Gl[4][16][64];   // 16 KB; (rg,c) thread-private per a
  __shared__ int hist[16];
  const int t = threadIdx.x;
  const int rg = t >> 6, c = t & 63;
  for (int idx = t; idx < 4096; idx += 256)
    ((float4*)Gl)[idx] = make_float4(0.f, 0.f, 0.f, 0.f);
  if (t < 16) hist[t] = 0;
  __syncthreads();
  const int r0 = blockIdx.x * 64;
  for (int k = 0; k < 16; ++k) {
    const int r = r0 + k * 4 + rg;
    float4 v = ((const float4*)(P + (size_t)r * DK))[c];
    ushort4 h;
    __hip_bfloat16 b;
    b = __float2bfloat16(v.x); h.x = __builtin_bit_cast(unsigned short, b);
    b = __float2bfloat16(v.y); h.y = __builtin_bit_cast(unsigned short, b);
    b = __float2bfloat16(v.z); h.z = __builtin_bit_cast(unsigned short, b);
    b = __float2bfloat16(v.w); h.w = __builtin_bit_cast(unsigned short, b);
    ((ushort4*)(Pb + (size_t)r * DK))[c] = h;
    const int a = aff[r];
    float4 g = Gl[rg][a][c];
    g.x += v.x; g.y += v.y; g.z += v.z; g.w += v.w;
    Gl[rg][a][c] = g;
  }
  if (t < 64) {
    const int g = r0 + t;
    const int a = aff[g];
    keys[g] = (a << 12) | inst[g];
    atomicAdd(&hist[a], 1);
  }
  __syncthreads();
  if (t < 16) atomicAdd(&cntA[t], hist[t]);
  for (int idx = t; idx < 1024; idx += 256) {
    const int a = idx >> 6, cc = idx & 63;
    float4 s0 = Gl[0][a][cc], s1 = Gl[1][a][cc];
    float4 s2 = Gl[2][a][cc], s3 = Gl[3][a][cc];
    atomicAdd(&G[a * 256 + cc * 4 + 0], s0.x + s1.x + s2.x + s3.x);
    atomicAdd(&G[a * 256 + cc * 4 + 1], s0.y + s1.y + s2.y + s3.y);
    atomicAdd(&G[a * 256 + cc * 4 + 2], s0.z + s1.z + s2.z + s3.z);
    atomicAdd(&G[a * 256 + cc * 4 + 3], s0.w + s1.w + s2.w + s3.w);
  }
}

// ---- fused GEMM: 256x256 tile, 16x16x32 MFMA, m201-style 8-phase schedule ----
// LDS rows = 128 B (K-tile of 64 bf16), 8 16B-slots. Swizzle: slot =
// (ks*4+q) ^ (row&7) with q=l>>4, row frag = l&15 — the R1/R2 layout that
// measured ZERO bank conflicts. Source pre-swizzled, LDS dest lane-linear.
__global__ __launch_bounds__(512, 1) void fused_kernel(
    const ushort* __restrict__ Pb, float2* __restrict__ stats) {
  __shared__ __align__(16) char Ab[2 * 32768];   // [dbuf][256 rows][128B]
  __shared__ __align__(16) char Bb[2 * 32768];
  __shared__ float2 red[4][256];                 // 8KB epilogue merge

  const int tid = threadIdx.x;
  const int w = tid >> 6;        // 0..7
  const int l = tid & 63;
  const int li = l & 15;
  const int q = l >> 4;          // 0..3
  const int iw = w >> 2;         // 0..1 : 128 i-rows each
  const int jw = w & 3;          // 0..3 : 64 j-cols each

  const int bid = blockIdx.x;
  const int jc = (bid & 7) * 4 + ((bid >> 3) & 3);  // XCD-locked j-chunk 0..31
  const int it = bid >> 5;                          // 0..31
  const int ibase = it * 256;
  const int jcbase = jc * 256;

  const char* gA = (const char*)(Pb + (size_t)ibase * DK);
  const char* gB = (const char*)(Pb + (size_t)jcbase * DK);

  // staging constants
  const int srr = tid >> 3;        // 0..63
  const int ssl = tid & 7;
  const int sswzA = (ssl ^ (srr & 7)) * 16;
  const int brr = (tid >> 3) & 31; // 0..31
  const int bg2 = tid >> 8;        // 0..1
  const int sswzB = (ssl ^ (brr & 7)) * 16;

  // A half H = rows {H*64..H*64+63} U {128+H*64..+63}  (bit6 of row == H)
#define STAGE_A(KT, H)                                                         \
  {                                                                            \
    const int d1 = (KT) & 1;                                                   \
    const int ko = (KT) * 128;                                                 \
    const int r0 = (H) * 64 + srr, r1 = 128 + (H) * 64 + srr;                  \
    gload16(gA + (size_t)r0 * 512 + ko + sswzA,                                \
            Ab + d1 * 32768 + r0 * 128 + ssl * 16);                            \
    gload16(gA + (size_t)r1 * 512 + ko + sswzA,                                \
            Ab + d1 * 32768 + r1 * 128 + ssl * 16);                            \
  }
  // B half H = rows with bit5 == H (each wave's nh-half of its 64 cols)
#define STAGE_B(KT, H)                                                         \
  {                                                                            \
    const int d1 = (KT) & 1;                                                   \
    const int ko = (KT) * 128;                                                 \
    const int r0 = bg2 * 64 + (H) * 32 + brr;                                  \
    const int r1 = (2 + bg2) * 64 + (H) * 32 + brr;                            \
    gload16(gB + (size_t)r0 * 512 + ko + sswzB,                                \
            Bb + d1 * 32768 + r0 * 128 + ssl * 16);                            \
    gload16(gB + (size_t)r1 * 512 + ko + sswzB,                                \
            Bb + d1 * 32768 + r1 * 128 + ssl * 16);                            \
  }

#define BAR __builtin_amdgcn_s_barrier()
#define LGKM0 asm volatile("s_waitcnt lgkmcnt(0)" ::: "memory")
#define SB0 __builtin_amdgcn_sched_barrier(0)

  // per-lane fragment read constants (R2-verified swizzle)
  const int rx = li & 7;
  const int off0 = ((0 * 4 + q) ^ rx) * 16;   // kstep 0
  const int off1 = ((1 * 4 + q) ^ rx) * 16;   // kstep 1
  const int rowA = (iw * 128 + li) * 128;     // + MH*8192 + m*2048
  const int rowB = (jw * 64 + li) * 128;      // + NH*4096 + n*2048

#define READ_A(MH)                                                             \
  _Pragma("unroll") for (int m = 0; m < 4; ++m) {                              \
    af[m][0] = *(const vshort8*)(As + rowA + (MH) * 8192 + m * 2048 + off0);   \
    af[m][1] = *(const vshort8*)(As + rowA + (MH) * 8192 + m * 2048 + off1);   \
  }
#define READ_B(NH)                                                             \
  _Pragma("unroll") for (int n = 0; n < 2; ++n) {                              \
    bf[(NH)*2+n][0] = *(const vshort8*)(Bs + rowB + (NH)*4096 + n*2048 + off0);\
    bf[(NH)*2+n][1] = *(const vshort8*)(Bs + rowB + (NH)*4096 + n*2048 + off1);\
  }
#define DO_MFMA(MH, NH)                                                        \
  __builtin_amdgcn_s_setprio(1);                                               \
  _Pragma("unroll") for (int ks = 0; ks < 2; ++ks)                             \
    _Pragma("unroll") for (int m = 0; m < 4; ++m) {                            \
      acc[(MH)*4+m][(NH)*2+0] = __builtin_amdgcn_mfma_f32_16x16x32_bf16(       \
          bf[(NH)*2+0][ks], af[m][ks], acc[(MH)*4+m][(NH)*2+0], 0, 0, 0);      \
      acc[(MH)*4+m][(NH)*2+1] = __builtin_amdgcn_mfma_f32_16x16x32_bf16(       \
          bf[(NH)*2+1][ks], af[m][ks], acc[(MH)*4+m][(NH)*2+1], 0, 0, 0);      \
    }                                                                          \
  __builtin_amdgcn_s_setprio(0);

  vfloat4 acc[8][4];
#pragma unroll
  for (int mf = 0; mf < 8; ++mf)
#pragma unroll
    for (int nf = 0; nf < 4; ++nf) acc[mf][nf] = (vfloat4){0.f, 0.f, 0.f, 0.f};

  vshort8 af[4][2], bf[4][2];

  // prologue: stage tile 0 (order A0,B0,B1,A1); wait oldest 2 halves
  STAGE_A(0, 0) STAGE_B(0, 0) STAGE_B(0, 1) STAGE_A(0, 1)
  asm volatile("s_waitcnt vmcnt(4)" ::: "memory");
  BAR;

#pragma unroll
  for (int t = 0; t < 4; ++t) {
    const char* As = Ab + (t & 1) * 32768;
    const char* Bs = Bb + (t & 1) * 32768;
    // ---- P0: read Ah0+Bh0, stage next A0; MFMA (0,0) ----
    READ_A(0) READ_B(0)
    if (t < 3) STAGE_A(t + 1, 0)
    BAR; LGKM0; SB0;
    DO_MFMA(0, 0)
    if (t < 3) { asm volatile("s_waitcnt vmcnt(2)" ::: "memory"); }
    else       { asm volatile("s_waitcnt vmcnt(0)" ::: "memory"); }
    BAR;
    // ---- P1: read Bh1, stage next B0; MFMA (0,1) ----
    READ_B(1)
    if (t < 3) STAGE_B(t + 1, 0)
    BAR; LGKM0; SB0;
    DO_MFMA(0, 1)
    BAR;
    // ---- P2: read Ah1, stage next B1; MFMA (1,0) ----
    READ_A(1)
    if (t < 3) STAGE_B(t + 1, 1)
    BAR; LGKM0; SB0;
    DO_MFMA(1, 0)
    BAR;
    // ---- P3: stage next A1; MFMA (1,1) ----
    if (t < 3) STAGE_A(t + 1, 1)
    BAR; LGKM0; SB0;
    DO_MFMA(1, 1)
    if (t < 3) { asm volatile("s_waitcnt vmcnt(4)" ::: "memory"); }
    BAR;
  }

  // ---- epilogue: self-mask, per-i-row max + exp-sum (D col = li = i) ----
#pragma unroll
  for (int mf = 0; mf < 8; ++mf) {
    const int gib = ibase + iw * 128 + mf * 16;
    float mx = NEGINF;
#pragma unroll
    for (int nf = 0; nf < 4; ++nf) {
      if (gib == jcbase + jw * 64 + nf * 16) {
#pragma unroll
        for (int r = 0; r < 4; ++r)
          if (q * 4 + r == li) acc[mf][nf][r] = NEGINF;
      }
#pragma unroll
      for (int r = 0; r < 4; ++r) mx = fmaxf(mx, acc[mf][nf][r]);
    }
    mx = fmaxf(mx, __shfl_xor(mx, 16));
    mx = fmaxf(mx, __shfl_xor(mx, 32));
    const float rc = -mx * KLOG2E_T;
    float sv = 0.f;
#pragma unroll
    for (int nf = 0; nf < 4; ++nf)
#pragma unroll
      for (int r = 0; r < 4; ++r)
        sv += exp2f(fmaf(acc[mf][nf][r], KLOG2E_T, rc));
    sv += __shfl_xor(sv, 16);
    sv += __shfl_xor(sv, 32);
    if (l < 16) red[jw][iw * 128 + mf * 16 + li] = make_float2(mx, sv);
  }
  __syncthreads();
  if (tid < 256) {  // merge the 4 j-waves per row, write stat slot jc
    float2 a = red[0][tid];
    float mm = a.x, ss = a.y;
#pragma unroll
    for (int j2 = 1; j2 < 4; ++j2) {
      float2 b = red[j2][tid];
      float M = fmaxf(mm, b.x);
      ss = ss * exp2f((mm - M) * KLOG2E_T) + b.y * exp2f((b.x - M) * KLOG2E_T);
      mm = M;
    }
    stats[(size_t)jc * BN + ibase + tid] = make_float2(mm, ss);
  }
}

// -------- per-row: merge 32 lse-partials + algebraic pos-sums (key scan) --------
__global__ __launch_bounds__(256) void final_rows(
    const float2* __restrict__ stats, const float* __restrict__ P,
    const float* __restrict__ G, const int* __restrict__ keys,
    const int* __restrict__ cntA, float2* __restrict__ part) {
  __shared__ int kL[8192];   // all keys, 32 KB
  __shared__ float cs[4], ps[4];
  const int t = threadIdx.x;
  for (int idx = t; idx < 2048; idx += 256)
    ((int4*)kL)[idx] = ((const int4*)keys)[idx];
  __syncthreads();

  const int rloc = t >> 6;    // 0..3
  const int lane = t & 63;
  const int i = blockIdx.x * 4 + rloc;

  // merge 32 (m,s) partials via shuffle tree (lanes replicated x2)
  float2 st = stats[(size_t)(lane & 31) * BN + i];
  float mm = st.x, ss = st.y;
#pragma unroll
  for (int off = 1; off < 32; off <<= 1) {
    float mo = __shfl_xor(mm, off);
    float so = __shfl_xor(ss, off);
    float M = fmaxf(mm, mo);
    ss = ss * exp2f((mm - M) * KLOG2E_T) + so * exp2f((mo - M) * KLOG2E_T);
    mm = M;
  }
  const float lse = logf(ss) + mm * INV_T;

  // Sum_pos sim = (P_i . G[a] - Sum_{key==} P_i . P_j) / T   (exact fp32)
  const int key = keys[i];
  const int a = key >> 12;
  const float4* Pi = (const float4*)(P + (size_t)i * 256);
  float4 p4 = Pi[lane];
  float4 g4 = ((const float4*)(G + a * 256))[lane];
  float acc = p4.x * g4.x + p4.y * g4.y + p4.z * g4.z + p4.w * g4.w;
  int cnt = 0;
  for (int jb = lane; jb < 8192; jb += 64) {
    if (kL[jb] == key) {   // same-key rows (includes self) — rare
      cnt++;
      const float4* Pj = (const float4*)(P + (size_t)jb * 256);
      float s = 0.f;
#pragma unroll 8
      for (int c = 0; c < 64; ++c) {
        float4 x = Pi[c], y = Pj[c];
        s += x.x * y.x + x.y * y.y + x.z * y.z + x.w * y.w;
      }
      acc -= s;
    }
  }
#pragma unroll
  for (int off = 1; off < 64; off <<= 1) {
    acc += __shfl_xor(acc, off);
    cnt += __shfl_xor(cnt, off);
  }
  const float pc = (float)(cntA[a] - cnt);
  const float contrib = pc * lse - acc * INV_T;

  if (lane == 0) { cs[rloc] = contrib; ps[rloc] = pc; }
  __syncthreads();
  if (t == 0)
    part[blockIdx.x] = make_float2(cs[0] + cs[1] + cs[2] + cs[3],
                                   ps[0] + ps[1] + ps[2] + ps[3]);
}

__global__ void finalize(const float2* __restrict__ part, float* __restrict__ out) {
  const int t = threadIdx.x;   // 256 threads
  float c = 0.f, p = 0.f;
  for (int k = t; k < 2048; k += 256) {
    float2 v = part[k];
    c += v.x;
    p += v.y;
  }
#pragma unroll
  for (int off = 1; off < 64; off <<= 1) {
    c += __shfl_xor(c, off);
    p += __shfl_xor(p, off);
  }
  __shared__ float cs[4], ps[4];
  if ((t & 63) == 0) { cs[t >> 6] = c; ps[t >> 6] = p; }
  __syncthreads();
  if (t == 0) {
    c = cs[0] + cs[1] + cs[2] + cs[3];
    p = ps[0] + ps[1] + ps[2] + ps[3];
    out[0] = (p > 0.f) ? (c / p) : 0.f;
  }
}

extern "C" void kernel_launch(void* const* d_in, const int* in_sizes, int n_in,
                              void* d_out, int out_size, void* d_ws, size_t ws_size,
                              hipStream_t stream) {
  const float* P = (const float*)d_in[0];
  const int* aff = (const int*)d_in[1];
  const int* inst = (const int*)d_in[2];
  char* ws = (char*)d_ws;
  ushort* Pb    = (ushort*)(ws);                      // 4 MB
  int*    keys  = (int*)(ws + 4194304);               // 32 KB
  // --- zero region (one memset): G | cntA ---
  float*  G     = (float*)(ws + 4227072);             // 16 KB (16x256)
  int*    cntA  = (int*)(ws + 4243456);               // 64 B
  float2* stats = (float2*)(ws + 4243520);            // 2 MB (32 x 8192 x 8B)
  float2* part  = (float2*)(ws + 6340672);            // 16 KB
  float* out = (float*)d_out;

  hipMemsetAsync(G, 0, 16448, stream);                // G + cntA = 0
  prep_g<<<128, 256, 0, stream>>>(P, aff, inst, Pb, keys, cntA, G);
  fused_kernel<<<1024, 512, 0, stream>>>(Pb, stats);
  final_rows<<<2048, 256, 0, stream>>>(stats, P, G, keys, cntA, part);
  finalize<<<1, 256, 0, stream>>>(part, out);
}